// Round 3
// baseline (697.186 us; speedup 1.0000x reference)
//
#include <hip/hip_runtime.h>

// Per-pixel diagonal RNN, fp32 in/out.
// h_t = leaky_relu(W_ih*x_t + W_hh*h_{t-1} + b_hh), T=50, 2M independent pixels.
// Traffic: x 419MB + out 419MB + weights 25MB = 864 MB -> 137 us @ 6.3 TB/s.
//
// R2 analysis (from R1 counters): harness dur_us includes ~526us of reset
// fills (two 1.678GB fillBuffer dispatches at ~263us each dominate the
// rocprof top-5; our kernel is NOT in the top-5 => its dispatch is < 260us,
// est. ~160us). Remaining gap to the 137us floor: per-wave load issued only
// 1 iteration (~70 cyc) before its waitcnt vs ~900 cyc HBM latency =>
// duty-cycle ragged. Fix: prefetch distance 2 (register triple-buffer),
// 2 streams/thread -> 4 loads in flight per wave, 64KB/CU.
// (R2 bench failed on GPU acquisition — resubmitting unchanged.)

typedef float f32x4 __attribute__((ext_vector_type(4)));

__device__ __forceinline__ f32x4 step4(f32x4 h, f32x4 xv, f32x4 wi, f32x4 wh, f32x4 b) {
    f32x4 r;
    float v;
    v = fmaf(wh.x, h.x, fmaf(wi.x, xv.x, b.x)); r.x = (v > 0.f) ? v : 0.01f * v;
    v = fmaf(wh.y, h.y, fmaf(wi.y, xv.y, b.y)); r.y = (v > 0.f) ? v : 0.01f * v;
    v = fmaf(wh.z, h.z, fmaf(wi.z, xv.z, b.z)); r.z = (v > 0.f) ? v : 0.01f * v;
    v = fmaf(wh.w, h.w, fmaf(wi.w, xv.w, b.w)); r.w = (v > 0.f) ? v : 0.01f * v;
    return r;
}

// Fast path: 2 float4 streams per thread, x prefetched 2 timesteps ahead.
__global__ __launch_bounds__(256) void pixel_rnn_pf2(
    const f32x4* __restrict__ x,      // (T, nvec)
    const f32x4* __restrict__ wih,    // (nvec)
    const f32x4* __restrict__ whh,    // (nvec)
    const f32x4* __restrict__ bhh,    // (nvec)
    f32x4* __restrict__ out,          // (T, nvec)
    int nvec, int T)
{
    const int half = nvec >> 1;                       // vectors per stream
    int tid = blockIdx.x * blockDim.x + threadIdx.x;
    if (tid >= half) return;

    size_t i0 = (size_t)tid;
    size_t i1 = (size_t)tid + (size_t)half;
    size_t stride = (size_t)nvec;

    // Weights: load once, keep in registers for the whole recurrence.
    f32x4 wi0 = wih[i0], wi1 = wih[i1];
    f32x4 wh0 = whh[i0], wh1 = whh[i1];
    f32x4 b0  = bhh[i0], b1  = bhh[i1];

    f32x4 h0 = (f32x4)0.f, h1 = (f32x4)0.f;

    if (T >= 2) {
        // Prime prefetch queue: t=0 and t=1 in flight.
        f32x4 xa0 = __builtin_nontemporal_load(&x[i0]);
        f32x4 xa1 = __builtin_nontemporal_load(&x[i1]);
        f32x4 xb0 = __builtin_nontemporal_load(&x[i0 + stride]);
        f32x4 xb1 = __builtin_nontemporal_load(&x[i1 + stride]);

        size_t idx0 = i0, idx1 = i1;

#pragma unroll 2
        for (int t = 0; t < T - 2; ++t) {
            // Issue t+2 loads BEFORE consuming t: 2 iterations of latency cover.
            f32x4 xn0 = __builtin_nontemporal_load(&x[idx0 + 2 * stride]);
            f32x4 xn1 = __builtin_nontemporal_load(&x[idx1 + 2 * stride]);

            h0 = step4(h0, xa0, wi0, wh0, b0);
            h1 = step4(h1, xa1, wi1, wh1, b1);

            __builtin_nontemporal_store(h0, &out[idx0]);
            __builtin_nontemporal_store(h1, &out[idx1]);

            idx0 += stride;
            idx1 += stride;
            xa0 = xb0; xa1 = xb1;   // rotate queue (renamed away by unroll)
            xb0 = xn0; xb1 = xn1;
        }

        // t = T-2
        h0 = step4(h0, xa0, wi0, wh0, b0);
        h1 = step4(h1, xa1, wi1, wh1, b1);
        __builtin_nontemporal_store(h0, &out[idx0]);
        __builtin_nontemporal_store(h1, &out[idx1]);
        idx0 += stride;
        idx1 += stride;

        // t = T-1
        h0 = step4(h0, xb0, wi0, wh0, b0);
        h1 = step4(h1, xb1, wi1, wh1, b1);
        __builtin_nontemporal_store(h0, &out[idx0]);
        __builtin_nontemporal_store(h1, &out[idx1]);
    } else {
        f32x4 xa0 = __builtin_nontemporal_load(&x[i0]);
        f32x4 xa1 = __builtin_nontemporal_load(&x[i1]);
        h0 = step4(h0, xa0, wi0, wh0, b0);
        h1 = step4(h1, xa1, wi1, wh1, b1);
        __builtin_nontemporal_store(h0, &out[i0]);
        __builtin_nontemporal_store(h1, &out[i1]);
    }
}

// Generic fallback (1 stream/thread) for nvec not divisible by 2 — same math.
__global__ __launch_bounds__(256) void pixel_rnn_kernel1(
    const f32x4* __restrict__ x,
    const f32x4* __restrict__ wih,
    const f32x4* __restrict__ whh,
    const f32x4* __restrict__ bhh,
    f32x4* __restrict__ out,
    int nvec, int T)
{
    int i = blockIdx.x * blockDim.x + threadIdx.x;
    if (i >= nvec) return;

    f32x4 wi = wih[i];
    f32x4 wh = whh[i];
    f32x4 b  = bhh[i];
    f32x4 h  = (f32x4)0.f;

    size_t idx = (size_t)i;
    size_t stride = (size_t)nvec;

#pragma unroll 2
    for (int t = 0; t < T; ++t) {
        f32x4 xv = __builtin_nontemporal_load(&x[idx]);
        h = step4(h, xv, wi, wh, b);
        __builtin_nontemporal_store(h, &out[idx]);
        idx += stride;
    }
}

extern "C" void kernel_launch(void* const* d_in, const int* in_sizes, int n_in,
                              void* d_out, int out_size, void* d_ws, size_t ws_size,
                              hipStream_t stream) {
    const f32x4* x   = (const f32x4*)d_in[0];
    const f32x4* wih = (const f32x4*)d_in[1];
    const f32x4* whh = (const f32x4*)d_in[2];
    const f32x4* bhh = (const f32x4*)d_in[3];
    f32x4* out = (f32x4*)d_out;

    int npix = in_sizes[1];          // Z*H*W = 2,097,152
    int T    = in_sizes[0] / npix;   // 50
    int nvec = npix / 4;             // float4 vectors = 524,288

    int block = 256;
    if ((nvec & 1) == 0) {
        int nthreads = nvec / 2;     // 262,144 -> 1024 blocks, 16 waves/CU
        int grid = (nthreads + block - 1) / block;
        pixel_rnn_pf2<<<grid, block, 0, stream>>>(x, wih, whh, bhh, out, nvec, T);
    } else {
        int grid = (nvec + block - 1) / block;
        pixel_rnn_kernel1<<<grid, block, 0, stream>>>(x, wih, whh, bhh, out, nvec, T);
    }
}

// Round 4
// 673.836 us; speedup vs baseline: 1.0347x; 1.0347x over previous
//
#include <hip/hip_runtime.h>

// Per-pixel diagonal RNN, fp32 in/out.
// h_t = leaky_relu(W_ih*x_t + W_hh*h_{t-1} + b_hh), T=50, 2M independent pixels.
// Traffic: x 419MB + out 419MB + weights 25MB = 864 MB.
//
// R4: REVERT to the R1 pf1 kernel (best measured: 678.9us total; kernel-only
// ~153us after subtracting two ~263us harness reset fills = ~5.6 TB/s mixed
// read+write, ~90% of realistic mixed-stream ceiling).
// Post-mortem of pf2 (distance-2 prefetch, 697.2us, +18us REGRESSION):
// MLP was already abundant at pf1 (16 waves/CU x 2 loads x 1KB = 32KB in
// flight vs ~4.6KB needed); deeper prefetch added register rotation copies
// and coarser vmcnt clustering for zero latency benefit. Same lesson as the
// GEMM pipelining nulls (m99/m131): don't hand-pipeline an MLP-rich loop.

typedef float f32x4 __attribute__((ext_vector_type(4)));

__device__ __forceinline__ f32x4 step4(f32x4 h, f32x4 xv, f32x4 wi, f32x4 wh, f32x4 b) {
    f32x4 r;
    float v;
    v = fmaf(wh.x, h.x, fmaf(wi.x, xv.x, b.x)); r.x = (v > 0.f) ? v : 0.01f * v;
    v = fmaf(wh.y, h.y, fmaf(wi.y, xv.y, b.y)); r.y = (v > 0.f) ? v : 0.01f * v;
    v = fmaf(wh.z, h.z, fmaf(wi.z, xv.z, b.z)); r.z = (v > 0.f) ? v : 0.01f * v;
    v = fmaf(wh.w, h.w, fmaf(wi.w, xv.w, b.w)); r.w = (v > 0.f) ? v : 0.01f * v;
    return r;
}

// 2 float4 streams per thread, x[t+1] prefetched into registers (distance 1).
__global__ __launch_bounds__(256) void pixel_rnn_kernel2(
    const f32x4* __restrict__ x,      // (T, nvec)
    const f32x4* __restrict__ wih,    // (nvec)
    const f32x4* __restrict__ whh,    // (nvec)
    const f32x4* __restrict__ bhh,    // (nvec)
    f32x4* __restrict__ out,          // (T, nvec)
    int nvec, int T)
{
    const int half = nvec >> 1;                       // vectors per stream
    int tid = blockIdx.x * blockDim.x + threadIdx.x;
    if (tid >= half) return;

    size_t i0 = (size_t)tid;
    size_t i1 = (size_t)tid + (size_t)half;

    // Weights: load once, keep in registers for the whole recurrence.
    f32x4 wi0 = wih[i0], wi1 = wih[i1];
    f32x4 wh0 = whh[i0], wh1 = whh[i1];
    f32x4 b0  = bhh[i0], b1  = bhh[i1];

    f32x4 h0 = (f32x4)0.f, h1 = (f32x4)0.f;

    size_t stride = (size_t)nvec;
    size_t idx0 = i0, idx1 = i1;

    // Prime the register double-buffer with t=0.
    f32x4 xc0 = __builtin_nontemporal_load(&x[idx0]);
    f32x4 xc1 = __builtin_nontemporal_load(&x[idx1]);

#pragma unroll 2
    for (int t = 0; t < T - 1; ++t) {
        // Prefetch t+1 BEFORE consuming t: these loads stay in flight under
        // the FMA chain + stores of step t.
        f32x4 xn0 = __builtin_nontemporal_load(&x[idx0 + stride]);
        f32x4 xn1 = __builtin_nontemporal_load(&x[idx1 + stride]);

        h0 = step4(h0, xc0, wi0, wh0, b0);
        h1 = step4(h1, xc1, wi1, wh1, b1);

        __builtin_nontemporal_store(h0, &out[idx0]);
        __builtin_nontemporal_store(h1, &out[idx1]);

        idx0 += stride;
        idx1 += stride;
        xc0 = xn0;
        xc1 = xn1;
    }

    // Epilogue: last timestep, no prefetch.
    h0 = step4(h0, xc0, wi0, wh0, b0);
    h1 = step4(h1, xc1, wi1, wh1, b1);
    __builtin_nontemporal_store(h0, &out[idx0]);
    __builtin_nontemporal_store(h1, &out[idx1]);
}

// Generic fallback (1 stream/thread) for nvec not divisible by 2 — same math.
__global__ __launch_bounds__(256) void pixel_rnn_kernel1(
    const f32x4* __restrict__ x,
    const f32x4* __restrict__ wih,
    const f32x4* __restrict__ whh,
    const f32x4* __restrict__ bhh,
    f32x4* __restrict__ out,
    int nvec, int T)
{
    int i = blockIdx.x * blockDim.x + threadIdx.x;
    if (i >= nvec) return;

    f32x4 wi = wih[i];
    f32x4 wh = whh[i];
    f32x4 b  = bhh[i];
    f32x4 h  = (f32x4)0.f;

    size_t idx = (size_t)i;
    size_t stride = (size_t)nvec;

#pragma unroll 2
    for (int t = 0; t < T; ++t) {
        f32x4 xv = __builtin_nontemporal_load(&x[idx]);
        h = step4(h, xv, wi, wh, b);
        __builtin_nontemporal_store(h, &out[idx]);
        idx += stride;
    }
}

extern "C" void kernel_launch(void* const* d_in, const int* in_sizes, int n_in,
                              void* d_out, int out_size, void* d_ws, size_t ws_size,
                              hipStream_t stream) {
    const f32x4* x   = (const f32x4*)d_in[0];
    const f32x4* wih = (const f32x4*)d_in[1];
    const f32x4* whh = (const f32x4*)d_in[2];
    const f32x4* bhh = (const f32x4*)d_in[3];
    f32x4* out = (f32x4*)d_out;

    int npix = in_sizes[1];          // Z*H*W = 2,097,152
    int T    = in_sizes[0] / npix;   // 50
    int nvec = npix / 4;             // float4 vectors = 524,288

    int block = 256;
    if ((nvec & 1) == 0) {
        int nthreads = nvec / 2;     // 262,144 -> 1024 blocks, 16 waves/CU
        int grid = (nthreads + block - 1) / block;
        pixel_rnn_kernel2<<<grid, block, 0, stream>>>(x, wih, whh, bhh, out, nvec, T);
    } else {
        int grid = (nvec + block - 1) / block;
        pixel_rnn_kernel1<<<grid, block, 0, stream>>>(x, wih, whh, bhh, out, nvec, T);
    }
}